// Round 3
// baseline (2102.310 us; speedup 1.0000x reference)
//
#include <hip/hip_runtime.h>
#include <hip/hip_bf16.h>

// Problem constants
#define BATCH 512
#define TT 60
#define EDIM 300
#define HDIM 512
#define KP1 2112         // padded K for head GEMM (2053 -> 2112)
#define MDIM 256
#define V48 2400000      // 50000 tokens * 48 runs

typedef __bf16 bf16x4 __attribute__((ext_vector_type(4)));
typedef __bf16 bf16x8 __attribute__((ext_vector_type(8)));
typedef float  f32x16 __attribute__((ext_vector_type(16)));

__device__ __forceinline__ float sigm(float x) {
    return 1.0f / (1.0f + __expf(-x));
}
__device__ __forceinline__ float tanh_fast(float x) {
    float e = __expf(-2.0f * fabsf(x));
    float r = (1.0f - e) / (1.0f + e);
    return x >= 0.0f ? r : -r;
}

// ---------------------------------------------------------------------------
// Fragment layouts (bf16; a "slot" is lane*8 elems = 16B):
// Wf (weights): [cg:32][c:7][T:32][lane:64][e:8], T = j*4 + nt*2 + plane
// A-fragment slot l of (c,jj,plane) = A[row = s*32 + (l&31)]
//                                      [k = c*128 + kg*64 + jj*16 + (l>>5)*8 + e]
//   emb part (c 0..2, k<384): gathered directly from embB (pre-split hi/lo table)
//   h part  (c 3..6): rotating per-step buffers XfH[t][tile][s][kg][ch:4][4096]
// Rows are PERMUTED (sorted by seqlen desc): rowinfo[r] -> (src,b,sl).
//
// PERSISTENT kernel, BARRIER-LIGHT GEMM: B fragments are loaded DIRECTLY from
// global (wf, L2-resident) into MFMA operand registers as coalesced 1KB loads
// -- no LDS staging, no per-chunk barriers, no vmcnt(0) drains. Waves run the
// 7-chunk K-loop as independent dataflow; s-pair redundant B reads dedupe in
// L1. Only 4 barriers/step remain (h-wait, zs-combine, zh, publish-drain).
// The h-wait sits just before the chunk-3 A-prefetch, so the cross-block
// publish->signal->poll->LLC-read chain hides under the 3 emb chunks.
// Per-step sync = per-tile LLC counter, ALL RELAXED (ordering from the
// vmcnt(0)-draining __syncthreads before the signal). No agent-scope
// release/acquire in the loop -> no L2 writeback/invalidate, weights stay
// L2-resident. c/h state in registers; h_state written once after the loop.
// CU pairing: blocks bx and bx+256 co-reside; tile k pairs with 15-k.
// ---------------------------------------------------------------------------

__global__ __launch_bounds__(256) void sort_rows(const int* __restrict__ sl1,
                                                 const int* __restrict__ sl2,
                                                 int* __restrict__ rowinfo,
                                                 unsigned* __restrict__ step_done) {
    __shared__ unsigned cnt[61];
    __shared__ unsigned off[61];
    int tid = threadIdx.x;
    if (tid < 61) cnt[tid] = 0;
    if (tid >= 64 && tid < 80) step_done[tid - 64] = 0;
    __syncthreads();
    for (int i = tid; i < 1024; i += 256) {
        int sl = (i < 512) ? sl1[i] : sl2[i - 512];
        atomicAdd(&cnt[60 - sl], 1u);
    }
    __syncthreads();
    if (tid == 0) {
        unsigned s = 0;
        for (int k = 0; k < 61; ++k) { off[k] = s; s += cnt[k]; }
    }
    __syncthreads();
    for (int i = tid; i < 1024; i += 256) {
        int sc = i >= 512;
        int b = i & 511;
        int sl = sc ? sl2[b] : sl1[b];
        unsigned pos = atomicAdd(&off[60 - sl], 1u);
        rowinfo[pos] = b | (sc << 15) | (sl << 20);
    }
}

// prep_w: lstm_kernel [812][2048] fp32 -> Wf (hi/lo split, k-remapped:
//   new k<300 -> kern k; 300..383 -> 0; >=384 -> kern k-84)
__global__ __launch_bounds__(256) void prep_w(const float* __restrict__ kern,
                                              __bf16* __restrict__ wf) {
    __shared__ float tile[64][65];
    int bk = blockIdx.x % 14;
    int bn = blockIdx.x / 14;
    int k0 = bk * 64, n0 = bn * 64;
    int tid = threadIdx.x;
#pragma unroll
    for (int i = 0; i < 16; ++i) {
        int id = i * 256 + tid;
        int kk = id >> 6, nn = id & 63;
        int kg = k0 + kk;
        int src = (kg < 300) ? kg : (kg >= 384 ? kg - 84 : -1);
        tile[kk][nn] = (src >= 0) ? kern[(size_t)src * 2048 + n0 + nn] : 0.0f;
    }
    __syncthreads();
    int gate = n0 >> 9;
    int nt = gate >> 1;
#pragma unroll
    for (int i = 0; i < 2; ++i) {
        int id = i * 256 + tid;          // 0..511 = nn(64) x k8(8)
        int nn = id >> 3, k8 = id & 7;
        bf16x8 hv, lv;
#pragma unroll
        for (int j = 0; j < 8; ++j) {
            float v = tile[k8 * 8 + j][nn];
            __bf16 h = (__bf16)v;
            hv[j] = h;
            lv[j] = (__bf16)(v - (float)h);
        }
        int cg = (((n0 & 511) >> 4) + (nn >> 4));
        int hc = nn & 15;
        int lzc = ((gate & 1) << 4) + hc;
        int kglob = k0 + k8 * 8;
        int c = kglob >> 7;
        int j = (kglob >> 4) & 7;
        int half = k8 & 1;
        size_t o = (size_t)cg * 114688 + c * 16384 + (j * 4 + nt * 2) * 512
                 + (half * 32 + lzc) * 8;
        *(bf16x8*)(wf + o) = hv;
        *(bf16x8*)(wf + o + 512) = lv;
    }
}

__global__ __launch_bounds__(256) void prep_w1(const float* __restrict__ W1,
                                               __bf16* __restrict__ w1h,
                                               __bf16* __restrict__ w1l) {
    __shared__ float tile[64][65];
    int bk = blockIdx.x % 33;
    int bn = blockIdx.x / 33;
    int k0 = bk * 64, n0 = bn * 64;
    int tid = threadIdx.x;
#pragma unroll
    for (int i = 0; i < 16; ++i) {
        int id = i * 256 + tid;
        int kk = id >> 6, nn = id & 63;
        int kg = k0 + kk;
        tile[kk][nn] = (kg < 2053) ? W1[(size_t)kg * MDIM + n0 + nn] : 0.0f;
    }
    __syncthreads();
#pragma unroll
    for (int i = 0; i < 2; ++i) {
        int id = i * 256 + tid;
        int nn = id >> 3, k8 = (id & 7) * 8;
        bf16x8 hv, lv;
#pragma unroll
        for (int j = 0; j < 8; ++j) {
            float v = tile[k8 + j][nn];
            __bf16 h = (__bf16)v;
            hv[j] = h;
            lv[j] = (__bf16)(v - (float)h);
        }
        size_t o = (size_t)(n0 + nn) * KP1 + k0 + k8;
        *(bf16x8*)(w1h + o) = hv;
        *(bf16x8*)(w1l + o) = lv;
    }
}

// prep_emb: embeddings [50000][300] fp32 -> embB [50000][hi:384 | lo:384] bf16
__global__ __launch_bounds__(256) void prep_emb(const float* __restrict__ emb,
                                                __bf16* __restrict__ embB) {
    int id = blockIdx.x * 256 + threadIdx.x;
    if (id >= V48) return;
    int tok = id / 48;
    int k8 = id - tok * 48;
    int k0 = k8 * 8;
    float vv[8];
    const float* er = emb + (size_t)tok * EDIM + k0;
    if (k0 + 8 <= EDIM) {
        float4 f0 = *(const float4*)er;
        float4 f1 = *(const float4*)(er + 4);
        vv[0] = f0.x; vv[1] = f0.y; vv[2] = f0.z; vv[3] = f0.w;
        vv[4] = f1.x; vv[5] = f1.y; vv[6] = f1.z; vv[7] = f1.w;
    } else if (k0 < EDIM) {          // k0 == 296: 4 real + 4 pad
        float4 f0 = *(const float4*)er;
        vv[0] = f0.x; vv[1] = f0.y; vv[2] = f0.z; vv[3] = f0.w;
        vv[4] = vv[5] = vv[6] = vv[7] = 0.f;
    } else {
#pragma unroll
        for (int j = 0; j < 8; ++j) vv[j] = 0.f;
    }
    bf16x8 hv, lv;
#pragma unroll
    for (int j = 0; j < 8; ++j) {
        __bf16 h = (__bf16)vv[j];
        hv[j] = h;
        lv[j] = (__bf16)(vv[j] - (float)h);
    }
    size_t o = (size_t)tok * 768 + k0;
    *(bf16x8*)(embB + o) = hv;
    *(bf16x8*)(embB + o + 384) = lv;
}

// ---------------------------------------------------------------------------
// Persistent fused LSTM: all 60 steps in one launch.
// 512 blocks x 256 thr = 16 tiles x 32 cg, 2 blocks/CU.
// ---------------------------------------------------------------------------
#define ZSTR 68

__global__ __launch_bounds__(256, 2) void lstm_all(
    const int* __restrict__ in1, const int* __restrict__ in2,
    const int* __restrict__ rowinfo,
    const __bf16* __restrict__ embB, const float* __restrict__ bias,
    const __bf16* __restrict__ wf,
    __bf16* __restrict__ XfH,
    unsigned* __restrict__ step_done,
    float* __restrict__ h_state) {

    int bx = blockIdx.x;
    int xcd = bx & 7;
    int loc = bx >> 3;                               // 0..63
    int u = loc >> 3;                                // 0..7
    int p = xcd & 1;
    // tile pairing: co-resident blocks (bx, bx+256) host tiles (k, 15-k)
    int bt = (u < 4) ? ((u << 1) | p) : (15 - (((u - 4) << 1) | p));
    int cg = ((xcd >> 1) << 3) | (loc & 7);          // cg octet per xcd-pair

    __shared__ float zs[2][64 * ZSTR];               // 34.8 KB split-k planes
    __shared__ __align__(16) __bf16 zh[2 * 2 * 64 * 8];  // 4 KB publish staging
    __shared__ int info_s[64];

    int tid = threadIdx.x;
    int w = tid >> 6, lane = tid & 63, l31 = lane & 31;
    int s = w >> 1, kg = w & 1;

    if (tid < 64) info_s[tid] = rowinfo[bt * 64 + tid];
    __syncthreads();
    int t_end = info_s[0] >> 20;                     // max seqlen in tile

    // this lane's A-row token stream
    int rowl = s * 32 + l31;
    int inf_r = info_s[rowl];
    const int* tokptr = ((((inf_r >> 15) & 1) ? in2 : in1)) + (inf_r & 511) * TT;

    // cell-update constants
    int hc16 = tid & 15;
    int hcol = (cg << 4) + hc16;
    float bi = bias[hcol], bj = bias[512 + hcol];
    float bfv = bias[1024 + hcol], bo = bias[1536 + hcol];

    // c/h state for this block's exclusive 64x16 slice
    float c_reg[4] = {0.f, 0.f, 0.f, 0.f};
    float h_reg[4] = {0.f, 0.f, 0.f, 0.f};

    // per-wave B base: seg(c,jj,nt,pl) = wbl + c*16384 + jj*2048 + nt*1024 + pl*512
    const __bf16* wbl = wf + (size_t)cg * 114688 + (size_t)kg * 8192 + lane * 8;

    int ew = kg * 64 + ((lane >> 5) << 3);           // emb k-base per lane
    size_t hw_off = (size_t)((s * 2 + kg) * 4) * 4096 + lane * 8;

    for (int t = 0; t < t_end; ++t) {
        f32x16 acc[2];
#pragma unroll
        for (int nt = 0; nt < 2; ++nt)
#pragma unroll
            for (int r = 0; r < 16; ++r) acc[nt][r] = 0.0f;

        int tok = tokptr[t];
        const __bf16* eb = embB + (size_t)tok * 768 + ew;
        const __bf16* hrd = XfH + ((size_t)t * 16 + bt) * 65536 + hw_off;

        // prologue: A(0) emb fragments (B(0) loaded in first loop body)
        bf16x8 aH[4], aL[4];
#pragma unroll
        for (int jj = 0; jj < 4; ++jj) {
            aH[jj] = *(const bf16x8*)(eb + jj * 16);
            aL[jj] = *(const bf16x8*)(eb + 384 + jj * 16);
        }

#pragma unroll
        for (int c = 0; c < 7; ++c) {
            // B(c): 16 coalesced 1KB loads straight into MFMA operand regs
            const __bf16* bc = wbl + c * 16384;
            bf16x8 bH[4][2], bL[4][2];
#pragma unroll
            for (int jj = 0; jj < 4; ++jj)
#pragma unroll
                for (int nt = 0; nt < 2; ++nt) {
                    bH[jj][nt] = *(const bf16x8*)(bc + jj * 2048 + nt * 1024);
                    bL[jj][nt] = *(const bf16x8*)(bc + jj * 2048 + nt * 1024 + 512);
                }

            // h-wait: needed only before chunk-3 A-prefetch (first h chunk).
            // Hides the publish->signal->poll->LLC chain under emb chunks 0-2.
            if (c == 2 && t > 0) {
                if (tid == 0) {
                    unsigned target = 32u * (unsigned)t;
                    int guard = 0;
                    while (__hip_atomic_load(step_done + bt, __ATOMIC_RELAXED,
                                             __HIP_MEMORY_SCOPE_AGENT) < target) {
                        __builtin_amdgcn_s_sleep(1);
                        if (++guard > (1 << 20)) break;   // never hang
                    }
                }
                __syncthreads();
            }

            // A(c+1) prefetch
            bf16x8 nH[4], nL[4];
            if (c < 6) {
                if (c < 2) {                         // emb chunks 1,2
                    const __bf16* en = eb + (c + 1) * 128;
#pragma unroll
                    for (int jj = 0; jj < 4; ++jj) {
                        nH[jj] = *(const bf16x8*)(en + jj * 16);
                        nL[jj] = *(const bf16x8*)(en + 384 + jj * 16);
                    }
                } else {                             // h chunks 3..6
                    const __bf16* An = hrd + (c - 2) * 4096;
#pragma unroll
                    for (int jj = 0; jj < 4; ++jj) {
                        nH[jj] = *(const bf16x8*)(An + jj * 1024);
                        nL[jj] = *(const bf16x8*)(An + jj * 1024 + 512);
                    }
                }
            }

#pragma unroll
            for (int jj = 0; jj < 4; ++jj)
#pragma unroll
                for (int nt = 0; nt < 2; ++nt) {
                    acc[nt] = __builtin_amdgcn_mfma_f32_32x32x16_bf16(aH[jj], bH[jj][nt], acc[nt], 0, 0, 0);
                    acc[nt] = __builtin_amdgcn_mfma_f32_32x32x16_bf16(aH[jj], bL[jj][nt], acc[nt], 0, 0, 0);
                    acc[nt] = __builtin_amdgcn_mfma_f32_32x32x16_bf16(aL[jj], bH[jj][nt], acc[nt], 0, 0, 0);
                }
            if (c < 6) {
#pragma unroll
                for (int jj = 0; jj < 4; ++jj) { aH[jj] = nH[jj]; aL[jj] = nL[jj]; }
            }
        }

        // ---- split-k: each kg plane written independently, ONE barrier ----
#pragma unroll
        for (int nt = 0; nt < 2; ++nt)
#pragma unroll
            for (int r = 0; r < 16; ++r) {
                int rl = s * 32 + (r & 3) + ((r >> 2) << 3) + ((lane >> 5) << 2);
                zs[kg][rl * ZSTR + nt * 32 + l31] = acc[nt][r];
            }
        __syncthreads();

        // ---- LSTM cell update: 64 rows x 16 h-cols, state in registers ----
#pragma unroll
        for (int i = 0; i < 4; ++i) {
            int rl = i * 16 + (tid >> 4);
            int info = info_s[rl];
            int sl = info >> 20;
            float zi = zs[0][rl * ZSTR + hc16]      + zs[1][rl * ZSTR + hc16]      + bi;
            float zj = zs[0][rl * ZSTR + 16 + hc16] + zs[1][rl * ZSTR + 16 + hc16] + bj;
            float zf = zs[0][rl * ZSTR + 32 + hc16] + zs[1][rl * ZSTR + 32 + hc16] + bfv;
            float zo = zs[0][rl * ZSTR + 48 + hc16] + zs[1][rl * ZSTR + 48 + hc16] + bo;
            float c_old = c_reg[i];
            float h_old = h_reg[i];
            float nc = c_old * sigm(zf + 1.0f) + sigm(zi) * tanh_fast(zj);
            float nh = tanh_fast(nc) * sigm(zo);
            bool valid = t < sl;
            float cs = valid ? nc : c_old;
            float hs = valid ? nh : h_old;
            c_reg[i] = cs;
            h_reg[i] = hs;
            __bf16 hh = (__bf16)hs;
            int grp = hc16 >> 3, e = hc16 & 7;
            zh[(grp * 64 + rl) * 8 + e] = hh;
            zh[((2 + grp) * 64 + rl) * 8 + e] = (__bf16)(hs - (float)hh);
        }
        __syncthreads();

        if (t + 1 < t_end) {
            // publish h-frag for step t+1 (device-scope store: bypasses L2 so
            // remote-XCD consumers can never read stale lines)
            int plane = tid >> 7;
            int grp = (tid >> 6) & 1;
            int rl = tid & 63;
            ulonglong2 uv = *(const ulonglong2*)(zh + ((plane * 2 + grp) * 64 + rl) * 8);
            int s2 = rl >> 5;
            size_t base = ((size_t)(t + 1) * 16 + bt) * 65536
                        + (size_t)((s2 * 2 + ((cg >> 2) & 1)) * 4 + (cg >> 3)) * 4096
                        + (cg & 3) * 1024 + plane * 512 + (grp * 32 + (rl & 31)) * 8;
            unsigned long long* dst = (unsigned long long*)(XfH + base);
            __hip_atomic_store(dst,     uv.x, __ATOMIC_RELAXED, __HIP_MEMORY_SCOPE_AGENT);
            __hip_atomic_store(dst + 1, uv.y, __ATOMIC_RELAXED, __HIP_MEMORY_SCOPE_AGENT);
        }
        // barrier drains vmcnt(0): publishes ACKed at LLC before tid0 signals
        __syncthreads();
        if (t + 1 < t_end && tid == 0)
            __hip_atomic_fetch_add(step_done + bt, 1u, __ATOMIC_RELAXED,
                                   __HIP_MEMORY_SCOPE_AGENT);
    }

    // final h writeback (original batch index layout), once per kernel
#pragma unroll
    for (int i = 0; i < 4; ++i) {
        int rl = i * 16 + (tid >> 4);
        int info = info_s[rl];
        int b = info & 511, sc = (info >> 15) & 1;
        h_state[(size_t)((sc << 9) + b) * HDIM + hcol] = h_reg[i];
    }
}

// ---------------------------------------------------------------------------
// Head stage 1: h_combined [512][2112] as bf16 hi/lo planes
// ---------------------------------------------------------------------------
__global__ __launch_bounds__(256) void head1(const float* __restrict__ h_state,
                                             const int* __restrict__ sl1,
                                             const int* __restrict__ sl2,
                                             __bf16* __restrict__ hch,
                                             __bf16* __restrict__ hcl) {
    int b = blockIdx.x;
    int tid = threadIdx.x;
    const float* h1 = h_state + (size_t)b * HDIM;
    const float* h2 = h_state + (size_t)(512 + b) * HDIM;
    size_t ro = (size_t)b * KP1;
    float l1 = (float)sl1[b] / (float)TT;
    float l2 = (float)sl2[b] / (float)TT;
    float part = 0.0f;
#pragma unroll
    for (int i = 0; i < 2; ++i) {
        int k = i * 256 + tid;
        float a = h1[k], c = h2[k];
        float sv = a - c;
        float mv = a * c;
        __bf16 xh;
        xh = (__bf16)a;  hch[ro + k] = xh;         hcl[ro + k] = (__bf16)(a - (float)xh);
        xh = (__bf16)c;  hch[ro + 513 + k] = xh;   hcl[ro + 513 + k] = (__bf16)(c - (float)xh);
        xh = (__bf16)sv; hch[ro + 1026 + k] = xh;  hcl[ro + 1026 + k] = (__bf16)(sv - (float)xh);
        xh = (__bf16)mv; hch[ro + 1540 + k] = xh;  hcl[ro + 1540 + k] = (__bf16)(mv - (float)xh);
        part += sv * sv;
    }
    __shared__ float red[4];
#pragma unroll
    for (int off = 32; off > 0; off >>= 1) part += __shfl_down(part, off, 64);
    if ((tid & 63) == 0) red[tid >> 6] = part;
    __syncthreads();
    if (tid == 0) {
        float d = red[0] + red[1] + red[2] + red[3];
        float ls = l1 - l2;
        d += ls * ls;
        float vals[5] = {l1, l2, ls, d, l1 * l2};
        int pos[5] = {512, 1025, 1538, 1539, 2052};
#pragma unroll
        for (int i = 0; i < 5; ++i) {
            __bf16 xh = (__bf16)vals[i];
            hch[ro + pos[i]] = xh;
            hcl[ro + pos[i]] = (__bf16)(vals[i] - (float)xh);
        }
    }
}

// ---------------------------------------------------------------------------
// Head stage 2 (MFMA): partials over 4 k-slices of 528
// ---------------------------------------------------------------------------
__global__ __launch_bounds__(512, 2) void head2m(
    const __bf16* __restrict__ hch, const __bf16* __restrict__ hcl,
    const __bf16* __restrict__ w1h, const __bf16* __restrict__ w1l,
    float* __restrict__ part) {

    __shared__ __align__(16) __bf16 Bb[2][64 * 512];

    int tid = threadIdx.x;
    int bx = blockIdx.x;
    int mt = bx >> 3;
    int n2 = (bx >> 2) & 1;
    int ks = bx & 3;
    int w = tid >> 6, lane = tid & 63, l31 = lane & 31;
    int half8 = (lane >> 5) << 3;
    int s = w >> 1, nh = w & 1;
    int kbase = ks * 528;

    int k8 = tid & 15;
    int jb = k8 >> 1;
    int rb = (tid >> 4) & 31;
    size_t gboff[8];
    int lo[8];
#pragma unroll
    for (int i = 0; i < 8; ++i) {
        int r = ((i & 3) << 5) + rb;
        int plane = i >> 2;
        int ng = n2 * 128 + r;
        gboff[i] = (size_t)ng * KP1 + k8 * 8;
        int nt = r >> 5;
        int colp = ((r & 31) + (jb << 2)) & 31;
        lo[i] = ((((jb << 2) + nt) << 1) + plane) * 512 + (colp + ((k8 & 1) << 5)) * 8;
    }

    const __bf16* Ah0 = hch + (size_t)(mt * 128 + s * 32 + l31) * KP1 + kbase + half8;
    const __bf16* Al0 = hcl + (size_t)(mt * 128 + s * 32 + l31) * KP1 + kbase + half8;

    bf16x8 rB[8];
    f32x16 acc[2];
#pragma unroll
    for (int nt = 0; nt < 2; ++nt)
#pragma unroll
        for (int r = 0; r < 16; ++r) acc[nt][r] = 0.0f;

#pragma unroll
    for (int i = 0; i < 8; ++i)
        rB[i] = *(const bf16x8*)(((i >= 4) ? w1l : w1h) + gboff[i] + kbase);
#pragma unroll
    for (int i = 0; i < 8; ++i) *(bf16x8*)(&Bb[0][lo[i]]) = rB[i];
    __syncthreads();

    for (int c = 0; c < 5; ++c) {
        int cur = c & 1;
        if (c < 4) {
            int k0 = kbase + (c + 1) * 128;
            bool tail = (c + 1 == 4);
#pragma unroll
            for (int i = 0; i < 8; ++i) {
                if (!tail || k8 < 2)
                    rB[i] = *(const bf16x8*)(((i >= 4) ? w1l : w1h) + gboff[i] + k0);
            }
        }
        int jmax = (c == 4) ? 1 : 8;
        for (int j = 0; j < jmax; ++j) {
            bf16x8 ah = *(const bf16x8*)(Ah0 + c * 128 + j * 16);
            bf16x8 al = *(const bf16x8*)(Al0 + c * 128 + j * 16);
            int cp = ((l31 + (j << 2)) & 31) + ((lane >> 5) << 5);
#pragma unroll
            for (int ntl = 0; ntl < 2; ++ntl) {
                int ntg = nh * 2 + ntl;
                const __bf16* bp = &Bb[cur][(((j << 2) + ntg) << 1) * 512 + cp * 8];
                bf16x8 bh = *(const bf16x8*)bp;
                bf16x8 bl = *(const bf16x8*)(bp + 512);
                acc[ntl] = __builtin_amdgcn_mfma_f32_32x32x16_bf16(ah, bh, acc[ntl], 0, 0, 0);
                acc[ntl] = __builtin_amdgcn_mfma_f32_32x32x16_bf16(ah, bl, acc[ntl], 0, 0, 0);
                acc[ntl] = __builtin_amdgcn_mfma_f32_32x32x16_bf16(al, bh, acc[ntl], 0, 0, 0);
            }
        }
        if (c < 4) {
#pragma unroll
            for (int i = 0; i < 8; ++i) *(bf16x8*)(&Bb[1 - cur][lo[i]]) = rB[i];
        }
        __syncthreads();
    }

#pragma unroll
    for (int ntl = 0; ntl < 2; ++ntl)
#pragma unroll
        for (int r = 0; r < 16; ++r) {
            int row = mt * 128 + s * 32 + (r & 3) + ((r >> 2) << 3) + ((lane >> 5) << 2);
            int col = n2 * 128 + nh * 64 + ntl * 32 + l31;
            part[((size_t)ks * 512 + row) * MDIM + col] = acc[ntl][r];
        }
}

// ---------------------------------------------------------------------------
// Head stage 3: e1 = relu(sum partials + b1); out = e1 @ W2 + b2
// ---------------------------------------------------------------------------
__global__ __launch_bounds__(256) void head3(const float* __restrict__ part,
                                             const float* __restrict__ b1,
                                             const float* __restrict__ W2,
                                             const float* __restrict__ b2,
                                             float* __restrict__ out) {
    int row = blockIdx.x;
    int tid = threadIdx.x;
    float sv = b1[tid];
#pragma unroll
    for (int ks = 0; ks < 4; ++ks)
        sv += part[((size_t)ks * 512 + row) * MDIM + tid];
    float e = fmaxf(sv, 0.0f);
    float p0 = e * W2[tid * 2 + 0];
    float p1 = e * W2[tid * 2 + 1];
#pragma unroll
    for (int off = 32; off > 0; off >>= 1) {
        p0 += __shfl_down(p0, off, 64);
        p1 += __shfl_down(p1, off, 64);
    }
    __shared__ float r0[4], r1[4];
    if ((tid & 63) == 0) { r0[tid >> 6] = p0; r1[tid >> 6] = p1; }
    __syncthreads();
    if (tid == 0) out[row * 2 + 0] = r0[0] + r0[1] + r0[2] + r0[3] + b2[0];
    if (tid == 1) out[row * 2 + 1] = r1[0] + r1[1] + r1[2] + r1[3] + b2[1];
}

// ---------------------------------------------------------------------------
extern "C" void kernel_launch(void* const* d_in, const int* in_sizes, int n_in,
                              void* d_out, int out_size, void* d_ws, size_t ws_size,
                              hipStream_t stream) {
    const int*   in1  = (const int*)d_in[0];
    const int*   in2  = (const int*)d_in[1];
    const int*   sl1  = (const int*)d_in[2];
    const int*   sl2  = (const int*)d_in[3];
    const float* emb  = (const float*)d_in[4];
    const float* kern = (const float*)d_in[5];
    const float* bias = (const float*)d_in[6];
    const float* W1   = (const float*)d_in[7];
    const float* b1   = (const float*)d_in[8];
    const float* W2   = (const float*)d_in[9];
    const float* b2   = (const float*)d_in[10];
    float* out = (float*)d_out;

    char* ws = (char*)d_ws;
    // ws layout (bytes):
    //   rowinfo i32[1024]         @ 0            (4096)
    //   step_done u32[16]         @ 4096
    //   h_state f32 [1024*512]    @ 2,097,152    (2,097,152)
    //   wf  bf16 frag             @ 6,291,456    (7,340,032)
    //   hch bf16 [512*2112]       @ 13,631,488   (2,162,688)
    //   hcl                       @ 15,794,176   (2,162,688)
    //   w1h bf16 [256*2112]       @ 17,956,864   (1,081,344)
    //   w1l                       @ 19,038,208   (1,081,344)
    //   part f32 [4*512*256]      @ 20,119,552   (2,097,152)
    //   embB bf16 [50000][768]    @ 23,068,672   (76,800,000)
    //   XfH bf16 61*[16][65536]   @ 100,663,296  (127,926,272) -> 228,589,568
    int*      rowinfo   = (int*)ws;
    unsigned* step_done = (unsigned*)(ws + 4096u);
    float*  h_state = (float*)(ws + 2097152u);
    __bf16* wf   = (__bf16*)(ws + 6291456u);
    __bf16* hch  = (__bf16*)(ws + 13631488u);
    __bf16* hcl  = (__bf16*)(ws + 15794176u);
    __bf16* w1h  = (__bf16*)(ws + 17956864u);
    __bf16* w1l  = (__bf16*)(ws + 19038208u);
    float*  part = (float*)(ws + 20119552u);
    __bf16* embB = (__bf16*)(ws + 23068672u);
    __bf16* XfH  = (__bf16*)(ws + 100663296u);

    // zero hch/hcl pad columns
    hipMemsetAsync(ws + 13631488u, 0, 4325376u, stream);
    // zero XfH region 0 (initial h = 0)
    hipMemsetAsync(ws + 100663296u, 0, 2097152u, stream);

    sort_rows<<<dim3(1), dim3(256), 0, stream>>>(sl1, sl2, rowinfo, step_done);
    prep_w<<<dim3(14 * 32), dim3(256), 0, stream>>>(kern, wf);
    prep_w1<<<dim3(33 * 4), dim3(256), 0, stream>>>(W1, w1h, w1l);
    prep_emb<<<dim3(9375), dim3(256), 0, stream>>>(emb, embB);

    lstm_all<<<dim3(512), dim3(256), 0, stream>>>(
        in1, in2, rowinfo, embB, bias, wf, XfH, step_done, h_state);

    head1<<<dim3(512), dim3(256), 0, stream>>>(h_state, sl1, sl2, hch, hcl);
    head2m<<<dim3(32), dim3(512), 0, stream>>>(hch, hcl, w1h, w1l, part);
    head3<<<dim3(512), dim3(256), 0, stream>>>(part, b1, W2, b2, out);
}

// Round 5
// 1232.726 us; speedup vs baseline: 1.7054x; 1.7054x over previous
//
#include <hip/hip_runtime.h>
#include <hip/hip_bf16.h>

// Problem constants
#define BATCH 512
#define TT 60
#define EDIM 300
#define HDIM 512
#define KP1 2112         // padded K for head GEMM (2053 -> 2112)
#define MDIM 256
#define V48 2400000      // 50000 tokens * 48 runs

typedef __bf16 bf16x4 __attribute__((ext_vector_type(4)));
typedef __bf16 bf16x8 __attribute__((ext_vector_type(8)));
typedef float  f32x16 __attribute__((ext_vector_type(16)));

#define GLL16(g, l) __builtin_amdgcn_global_load_lds( \
    (const __attribute__((address_space(1))) void*)(g), \
    (__attribute__((address_space(3))) void*)(l), 16, 0, 0)

#define SBAR()  __builtin_amdgcn_s_barrier()
#define SCHED0() __builtin_amdgcn_sched_barrier(0)

__device__ __forceinline__ float sigm(float x) {
    return 1.0f / (1.0f + __expf(-x));
}
__device__ __forceinline__ float tanh_fast(float x) {
    float e = __expf(-2.0f * fabsf(x));
    float r = (1.0f - e) / (1.0f + e);
    return x >= 0.0f ? r : -r;
}

// ---------------------------------------------------------------------------
// Fragment layouts (bf16; a "slot" is lane*8 elems = 16B):
// Wf (weights): [cg:32][c:7][T:32][lane:64][e:8], T = j*4 + nt*2 + plane
// A-fragment slot l of (c,jj,plane) = A[row = s*32 + (l&31)]
//                                      [k = c*128 + kg*64 + jj*16 + (l>>5)*8 + e]
//   emb part (c 0..2): gathered from embB (pre-split hi/lo table)
//   h part  (c 3..6): rotating per-step buffers XfH[t][tile][s][kg][ch:4][4096]
//
// PERSISTENT kernel with COUNTED-VMCNT pipeline (T3/T4): B staged to LDS via
// global_load_lds double-buffer; in-loop barriers are RAW s_barrier preceded
// by s_waitcnt vmcnt(8) -- per iteration each wave issues exactly 8 GLL16
// (stage c+1) then 8 A-loads (prefetch c+1), so vmcnt(8) at iter top retires
// precisely stage(c) while keeping stage(c+1)+A(c+1) IN FLIGHT across the
// barrier (never vmcnt(0) in the loop). A raw s_barrier separates the end of
// the chunk loop from the zs overlay (round-4 bug: without it a fast wave
// overwrites Bb bytes a slower wave is still ds_reading for chunk 6).
// zs overlay spans BOTH buffers with stride 72 floats (bank-conflict-free;
// safe: both planes consumed before the next stage-writes, which are ordered
// after the zh barrier). Boundary uses lgkmcnt(0)-only barriers for LDS
// phases and vmcnt(16) before the step signal (retires the 2 publish stores,
// keeps next-step stage(0)+A(0) alive).
// Per-step sync = per-tile LLC counter, ALL RELAXED; c/h state in registers;
// CU pairing: blocks bx and bx+256 co-reside; tile k pairs with 15-k.
// ---------------------------------------------------------------------------

__global__ __launch_bounds__(256) void sort_rows(const int* __restrict__ sl1,
                                                 const int* __restrict__ sl2,
                                                 int* __restrict__ rowinfo,
                                                 unsigned* __restrict__ step_done) {
    __shared__ unsigned cnt[61];
    __shared__ unsigned off[61];
    int tid = threadIdx.x;
    if (tid < 61) cnt[tid] = 0;
    if (tid >= 64 && tid < 80) step_done[tid - 64] = 0;
    __syncthreads();
    for (int i = tid; i < 1024; i += 256) {
        int sl = (i < 512) ? sl1[i] : sl2[i - 512];
        atomicAdd(&cnt[60 - sl], 1u);
    }
    __syncthreads();
    if (tid == 0) {
        unsigned s = 0;
        for (int k = 0; k < 61; ++k) { off[k] = s; s += cnt[k]; }
    }
    __syncthreads();
    for (int i = tid; i < 1024; i += 256) {
        int sc = i >= 512;
        int b = i & 511;
        int sl = sc ? sl2[b] : sl1[b];
        unsigned pos = atomicAdd(&off[60 - sl], 1u);
        rowinfo[pos] = b | (sc << 15) | (sl << 20);
    }
}

// prep_w: lstm_kernel [812][2048] fp32 -> Wf (hi/lo split, k-remapped)
__global__ __launch_bounds__(256) void prep_w(const float* __restrict__ kern,
                                              __bf16* __restrict__ wf) {
    __shared__ float tile[64][65];
    int bk = blockIdx.x % 14;
    int bn = blockIdx.x / 14;
    int k0 = bk * 64, n0 = bn * 64;
    int tid = threadIdx.x;
#pragma unroll
    for (int i = 0; i < 16; ++i) {
        int id = i * 256 + tid;
        int kk = id >> 6, nn = id & 63;
        int kg = k0 + kk;
        int src = (kg < 300) ? kg : (kg >= 384 ? kg - 84 : -1);
        tile[kk][nn] = (src >= 0) ? kern[(size_t)src * 2048 + n0 + nn] : 0.0f;
    }
    __syncthreads();
    int gate = n0 >> 9;
    int nt = gate >> 1;
#pragma unroll
    for (int i = 0; i < 2; ++i) {
        int id = i * 256 + tid;          // 0..511 = nn(64) x k8(8)
        int nn = id >> 3, k8 = id & 7;
        bf16x8 hv, lv;
#pragma unroll
        for (int j = 0; j < 8; ++j) {
            float v = tile[k8 * 8 + j][nn];
            __bf16 h = (__bf16)v;
            hv[j] = h;
            lv[j] = (__bf16)(v - (float)h);
        }
        int cg = (((n0 & 511) >> 4) + (nn >> 4));
        int hc = nn & 15;
        int lzc = ((gate & 1) << 4) + hc;
        int kglob = k0 + k8 * 8;
        int c = kglob >> 7;
        int j = (kglob >> 4) & 7;
        int half = k8 & 1;
        size_t o = (size_t)cg * 114688 + c * 16384 + (j * 4 + nt * 2) * 512
                 + (half * 32 + lzc) * 8;
        *(bf16x8*)(wf + o) = hv;
        *(bf16x8*)(wf + o + 512) = lv;
    }
}

__global__ __launch_bounds__(256) void prep_w1(const float* __restrict__ W1,
                                               __bf16* __restrict__ w1h,
                                               __bf16* __restrict__ w1l) {
    __shared__ float tile[64][65];
    int bk = blockIdx.x % 33;
    int bn = blockIdx.x / 33;
    int k0 = bk * 64, n0 = bn * 64;
    int tid = threadIdx.x;
#pragma unroll
    for (int i = 0; i < 16; ++i) {
        int id = i * 256 + tid;
        int kk = id >> 6, nn = id & 63;
        int kg = k0 + kk;
        tile[kk][nn] = (kg < 2053) ? W1[(size_t)kg * MDIM + n0 + nn] : 0.0f;
    }
    __syncthreads();
#pragma unroll
    for (int i = 0; i < 2; ++i) {
        int id = i * 256 + tid;
        int nn = id >> 3, k8 = (id & 7) * 8;
        bf16x8 hv, lv;
#pragma unroll
        for (int j = 0; j < 8; ++j) {
            float v = tile[k8 + j][nn];
            __bf16 h = (__bf16)v;
            hv[j] = h;
            lv[j] = (__bf16)(v - (float)h);
        }
        size_t o = (size_t)(n0 + nn) * KP1 + k0 + k8;
        *(bf16x8*)(w1h + o) = hv;
        *(bf16x8*)(w1l + o) = lv;
    }
}

// prep_emb: embeddings [50000][300] fp32 -> embB [50000][hi:384 | lo:384] bf16
__global__ __launch_bounds__(256) void prep_emb(const float* __restrict__ emb,
                                                __bf16* __restrict__ embB) {
    int id = blockIdx.x * 256 + threadIdx.x;
    if (id >= V48) return;
    int tok = id / 48;
    int k8 = id - tok * 48;
    int k0 = k8 * 8;
    float vv[8];
    const float* er = emb + (size_t)tok * EDIM + k0;
    if (k0 + 8 <= EDIM) {
        float4 f0 = *(const float4*)er;
        float4 f1 = *(const float4*)(er + 4);
        vv[0] = f0.x; vv[1] = f0.y; vv[2] = f0.z; vv[3] = f0.w;
        vv[4] = f1.x; vv[5] = f1.y; vv[6] = f1.z; vv[7] = f1.w;
    } else if (k0 < EDIM) {          // k0 == 296: 4 real + 4 pad
        float4 f0 = *(const float4*)er;
        vv[0] = f0.x; vv[1] = f0.y; vv[2] = f0.z; vv[3] = f0.w;
        vv[4] = vv[5] = vv[6] = vv[7] = 0.f;
    } else {
#pragma unroll
        for (int j = 0; j < 8; ++j) vv[j] = 0.f;
    }
    bf16x8 hv, lv;
#pragma unroll
    for (int j = 0; j < 8; ++j) {
        __bf16 h = (__bf16)vv[j];
        hv[j] = h;
        lv[j] = (__bf16)(vv[j] - (float)h);
    }
    size_t o = (size_t)tok * 768 + k0;
    *(bf16x8*)(embB + o) = hv;
    *(bf16x8*)(embB + o + 384) = lv;
}

// ---------------------------------------------------------------------------
// Persistent fused LSTM: all 60 steps in one launch.
// 512 blocks x 256 thr = 16 tiles x 32 cg, 2 blocks/CU (68.3 KB LDS each).
// ---------------------------------------------------------------------------
#define ZSTR 72

__global__ __launch_bounds__(256, 2) void lstm_all(
    const int* __restrict__ in1, const int* __restrict__ in2,
    const int* __restrict__ rowinfo,
    const __bf16* __restrict__ embB, const float* __restrict__ bias,
    const __bf16* __restrict__ wf,
    __bf16* __restrict__ XfH,
    unsigned* __restrict__ step_done,
    float* __restrict__ h_state) {

    int bx = blockIdx.x;
    int xcd = bx & 7;
    int loc = bx >> 3;                               // 0..63
    int u = loc >> 3;                                // 0..7
    int p = xcd & 1;
    // tile pairing: co-resident blocks (bx, bx+256) host tiles (k, 15-k)
    int bt = (u < 4) ? ((u << 1) | p) : (15 - (((u - 4) << 1) | p));
    int cg = ((xcd >> 1) << 3) | (loc & 7);          // cg octet per xcd-pair

    __shared__ __align__(16) __bf16 Bb[2][16384];    // 64 KB B double-buffer
    __shared__ __align__(16) __bf16 zh[2048];        // 4 KB publish staging
    __shared__ int info_s[64];

    int tid = threadIdx.x;
    int w = tid >> 6, lane = tid & 63, l31 = lane & 31;
    int s = w >> 1, kg = w & 1;

    if (tid < 64) info_s[tid] = rowinfo[bt * 64 + tid];
    __syncthreads();
    int t_end = info_s[0] >> 20;                     // max seqlen in tile

    // this lane's A-row token stream
    int rowl = s * 32 + l31;
    int inf_r = info_s[rowl];
    const int* tokptr = ((((inf_r >> 15) & 1) ? in2 : in1)) + (inf_r & 511) * TT;

    // cell-update constants
    int hc16 = tid & 15;
    int hcol = (cg << 4) + hc16;
    float bi = bias[hcol], bj = bias[512 + hcol];
    float bfv = bias[1024 + hcol], bo = bias[1536 + hcol];

    // c/h state for this block's exclusive 64x16 slice
    float c_reg[4] = {0.f, 0.f, 0.f, 0.f};
    float h_reg[4] = {0.f, 0.f, 0.f, 0.f};

    const __bf16* wb = wf + (size_t)cg * 114688;
    auto stageB = [&](int c, int buf) {              // exactly 8 GLL16 / thread
        const __bf16* src = wb + c * 16384 + w * 4096 + lane * 8;
        __bf16* dst = &Bb[buf][w * 4096 + lane * 8];
#pragma unroll
        for (int i = 0; i < 8; ++i)
            GLL16(src + i * 512, dst + i * 512);
    };

    int ew = kg * 64 + ((lane >> 5) << 3);           // emb k-base per lane
    size_t hw_off = (size_t)((s * 2 + kg) * 4) * 4096 + lane * 8;

    // ---- prologue: tok(0) -> stage(0)->buf0 -> A(0) emb loads ----
    int tok = tokptr[0];                             // 1 vmem (oldest)
    stageB(0, 0);                                    // 8 vmem
    SCHED0();
    bf16x8 aH[4], aL[4];
    const __bf16* eb = embB + (size_t)tok * 768 + ew;
#pragma unroll
    for (int jj = 0; jj < 4; ++jj) {                 // 8 vmem
        aH[jj] = *(const bf16x8*)(eb + jj * 16);
        aL[jj] = *(const bf16x8*)(eb + 384 + jj * 16);
    }
    SCHED0();

    for (int t = 0; t < t_end; ++t) {
        f32x16 acc[2];
#pragma unroll
        for (int nt = 0; nt < 2; ++nt)
#pragma unroll
            for (int r = 0; r < 16; ++r) acc[nt][r] = 0.0f;

        const __bf16* hrd = XfH + ((size_t)t * 16 + bt) * 65536 + hw_off;

#pragma unroll
        for (int c = 0; c < 7; ++c) {
            int cur = (t + c) & 1;
            // stage(c) landed (8 newest outstanding = A(c), kept in flight)
            asm volatile("s_waitcnt vmcnt(8)" ::: "memory");
            SBAR();
            SCHED0();
            if (c == 2 && t > 0) {
                // h(t) published by all 32 blocks of this tile?
                if (tid == 0) {
                    unsigned target = 32u * (unsigned)t;
                    int guard = 0;
                    while (__hip_atomic_load(step_done + bt, __ATOMIC_RELAXED,
                                             __HIP_MEMORY_SCOPE_AGENT) < target) {
                        __builtin_amdgcn_s_sleep(1);
                        if (++guard > (1 << 20)) break;   // never hang
                    }
                }
                SBAR();
                SCHED0();
            }
            bf16x8 nH[4], nL[4];
            if (c < 6) {
                stageB(c + 1, 1 - cur);              // 8 vmem
                SCHED0();
                if (c < 2) {                         // emb chunks 1,2: 8 vmem
                    const __bf16* en = eb + (c + 1) * 128;
#pragma unroll
                    for (int jj = 0; jj < 4; ++jj) {
                        nH[jj] = *(const bf16x8*)(en + jj * 16);
                        nL[jj] = *(const bf16x8*)(en + 384 + jj * 16);
                    }
                } else {                             // h chunks 3..6: 8 vmem
                    const __bf16* An = hrd + (c - 2) * 4096;
#pragma unroll
                    for (int jj = 0; jj < 4; ++jj) {
                        nH[jj] = *(const bf16x8*)(An + jj * 1024);
                        nL[jj] = *(const bf16x8*)(An + jj * 1024 + 512);
                    }
                }
                SCHED0();
            }
#pragma unroll
            for (int jj = 0; jj < 4; ++jj) {
                int j = kg * 4 + jj;
#pragma unroll
                for (int nt = 0; nt < 2; ++nt) {
                    int T0 = (j * 4 + nt * 2) * 512 + lane * 8;
                    bf16x8 bh = *(const bf16x8*)(&Bb[cur][T0]);
                    bf16x8 bl = *(const bf16x8*)(&Bb[cur][T0 + 512]);
                    acc[nt] = __builtin_amdgcn_mfma_f32_32x32x16_bf16(aH[jj], bh, acc[nt], 0, 0, 0);
                    acc[nt] = __builtin_amdgcn_mfma_f32_32x32x16_bf16(aH[jj], bl, acc[nt], 0, 0, 0);
                    acc[nt] = __builtin_amdgcn_mfma_f32_32x32x16_bf16(aL[jj], bh, acc[nt], 0, 0, 0);
                }
            }
            if (c < 6) {
#pragma unroll
                for (int jj = 0; jj < 4; ++jj) { aH[jj] = nH[jj]; aL[jj] = nL[jj]; }
            }
        }

        // ---- step boundary (outstanding vmem = 0 here) ----
        // Barrier: a wave reaching here has consumed its chunk-6 ds_reads,
        // but other waves may still be reading Bb -> must sync before the
        // zs overlay writes (round-4 bug).
        SBAR();
        SCHED0();

        int tn = (t + 1 < TT) ? t + 1 : TT - 1;
        int tok_n = tokptr[tn];                      // 1 vmem, issued early
        SCHED0();

        // split-k combine: zs overlays BOTH buffers, stride 72 floats
        // (36.9 KB of the 64 KB region; conflict-free on write and read)
        float* zsb = (float*)&Bb[0][0];              // [kg:2][rl:64][col:72] f32
#pragma unroll
        for (int nt = 0; nt < 2; ++nt)
#pragma unroll
            for (int r = 0; r < 16; ++r) {
                int rl = s * 32 + (r & 3) + ((r >> 2) << 3) + ((lane >> 5) << 2);
                zsb[kg * 4608 + rl * ZSTR + nt * 32 + l31] = acc[nt][r];
            }
        asm volatile("s_waitcnt lgkmcnt(0)" ::: "memory");
        SBAR();
        SCHED0();

        // ---- LSTM cell update: state in registers ----
#pragma unroll
        for (int i = 0; i < 4; ++i) {
            int rl = i * 16 + (tid >> 4);
            int info = info_s[rl];
            int sl = info >> 20;
            float zi = zsb[rl * ZSTR + hc16]      + zsb[4608 + rl * ZSTR + hc16]      + bi;
            float zj = zsb[rl * ZSTR + 16 + hc16] + zsb[4608 + rl * ZSTR + 16 + hc16] + bj;
            float zf = zsb[rl * ZSTR + 32 + hc16] + zsb[4608 + rl * ZSTR + 32 + hc16] + bfv;
            float zo = zsb[rl * ZSTR + 48 + hc16] + zsb[4608 + rl * ZSTR + 48 + hc16] + bo;
            float c_old = c_reg[i];
            float h_old = h_reg[i];
            float nc = c_old * sigm(zf + 1.0f) + sigm(zi) * tanh_fast(zj);
            float nh = tanh_fast(nc) * sigm(zo);
            bool valid = t < sl;
            float cs = valid ? nc : c_old;
            float hs = valid ? nh : h_old;
            c_reg[i] = cs;
            h_reg[i] = hs;
            __bf16 hh = (__bf16)hs;
            int grp = hc16 >> 3, e = hc16 & 7;
            zh[(grp * 64 + rl) * 8 + e] = hh;
            zh[((2 + grp) * 64 + rl) * 8 + e] = (__bf16)(hs - (float)hh);
        }
        asm volatile("s_waitcnt lgkmcnt(0)" ::: "memory");
        SBAR();
        SCHED0();

        if (t + 1 < t_end) {
            // publish h-frag for step t+1 (2 sc1 stores; bypass L2)
            int plane = tid >> 7;
            int grp = (tid >> 6) & 1;
            int rl = tid & 63;
            ulonglong2 uv = *(const ulonglong2*)(zh + ((plane * 2 + grp) * 64 + rl) * 8);
            int s2 = rl >> 5;
            size_t base = ((size_t)(t + 1) * 16 + bt) * 65536
                        + (size_t)((s2 * 2 + ((cg >> 2) & 1)) * 4 + (cg >> 3)) * 4096
                        + (cg & 3) * 1024 + plane * 512 + (grp * 32 + (rl & 31)) * 8;
            unsigned long long* dst = (unsigned long long*)(XfH + base);
            __hip_atomic_store(dst,     uv.x, __ATOMIC_RELAXED, __HIP_MEMORY_SCOPE_AGENT);
            __hip_atomic_store(dst + 1, uv.y, __ATOMIC_RELAXED, __HIP_MEMORY_SCOPE_AGENT);
            SCHED0();
            // next-step prefetch: stage(0) then A(0) (16 newest vmem)
            stageB(0, (t + 1) & 1);
            SCHED0();
            eb = embB + (size_t)tok_n * 768 + ew;
#pragma unroll
            for (int jj = 0; jj < 4; ++jj) {
                aH[jj] = *(const bf16x8*)(eb + jj * 16);
                aL[jj] = *(const bf16x8*)(eb + 384 + jj * 16);
            }
            SCHED0();
            // retire the 2 publish stores (ACKed at LLC); keep 16 newest alive
            asm volatile("s_waitcnt vmcnt(16)" ::: "memory");
            SBAR();
            if (tid == 0)
                __hip_atomic_fetch_add(step_done + bt, 1u, __ATOMIC_RELAXED,
                                       __HIP_MEMORY_SCOPE_AGENT);
        }
    }

    // final h writeback (original batch index layout), once per kernel
#pragma unroll
    for (int i = 0; i < 4; ++i) {
        int rl = i * 16 + (tid >> 4);
        int info = info_s[rl];
        int b = info & 511, sc = (info >> 15) & 1;
        h_state[(size_t)((sc << 9) + b) * HDIM + hcol] = h_reg[i];
    }
}

// ---------------------------------------------------------------------------
// Head stage 1: h_combined [512][2112] as bf16 hi/lo planes
// ---------------------------------------------------------------------------
__global__ __launch_bounds__(256) void head1(const float* __restrict__ h_state,
                                             const int* __restrict__ sl1,
                                             const int* __restrict__ sl2,
                                             __bf16* __restrict__ hch,
                                             __bf16* __restrict__ hcl) {
    int b = blockIdx.x;
    int tid = threadIdx.x;
    const float* h1 = h_state + (size_t)b * HDIM;
    const float* h2 = h_state + (size_t)(512 + b) * HDIM;
    size_t ro = (size_t)b * KP1;
    float l1 = (float)sl1[b] / (float)TT;
    float l2 = (float)sl2[b] / (float)TT;
    float part = 0.0f;
#pragma unroll
    for (int i = 0; i < 2; ++i) {
        int k = i * 256 + tid;
        float a = h1[k], c = h2[k];
        float sv = a - c;
        float mv = a * c;
        __bf16 xh;
        xh = (__bf16)a;  hch[ro + k] = xh;         hcl[ro + k] = (__bf16)(a - (float)xh);
        xh = (__bf16)c;  hch[ro + 513 + k] = xh;   hcl[ro + 513 + k] = (__bf16)(c - (float)xh);
        xh = (__bf16)sv; hch[ro + 1026 + k] = xh;  hcl[ro + 1026 + k] = (__bf16)(sv - (float)xh);
        xh = (__bf16)mv; hch[ro + 1540 + k] = xh;  hcl[ro + 1540 + k] = (__bf16)(mv - (float)xh);
        part += sv * sv;
    }
    __shared__ float red[4];
#pragma unroll
    for (int off = 32; off > 0; off >>= 1) part += __shfl_down(part, off, 64);
    if ((tid & 63) == 0) red[tid >> 6] = part;
    __syncthreads();
    if (tid == 0) {
        float d = red[0] + red[1] + red[2] + red[3];
        float ls = l1 - l2;
        d += ls * ls;
        float vals[5] = {l1, l2, ls, d, l1 * l2};
        int pos[5] = {512, 1025, 1538, 1539, 2052};
#pragma unroll
        for (int i = 0; i < 5; ++i) {
            __bf16 xh = (__bf16)vals[i];
            hch[ro + pos[i]] = xh;
            hcl[ro + pos[i]] = (__bf16)(vals[i] - (float)xh);
        }
    }
}

// ---------------------------------------------------------------------------
// Head stage 2 (MFMA): partials over 4 k-slices of 528
// ---------------------------------------------------------------------------
__global__ __launch_bounds__(512, 2) void head2m(
    const __bf16* __restrict__ hch, const __bf16* __restrict__ hcl,
    const __bf16* __restrict__ w1h, const __bf16* __restrict__ w1l,
    float* __restrict__ part) {

    __shared__ __align__(16) __bf16 Bb[2][64 * 512];

    int tid = threadIdx.x;
    int bx = blockIdx.x;
    int mt = bx >> 3;
    int n2 = (bx >> 2) & 1;
    int ks = bx & 3;
    int w = tid >> 6, lane = tid & 63, l31 = lane & 31;
    int half8 = (lane >> 5) << 3;
    int s = w >> 1, nh = w & 1;
    int kbase = ks * 528;

    int k8 = tid & 15;
    int jb = k8 >> 1;
    int rb = (tid >> 4) & 31;
    size_t gboff[8];
    int lo[8];
#pragma unroll
    for (int i = 0; i < 8; ++i) {
        int r = ((i & 3) << 5) + rb;
        int plane = i >> 2;
        int ng = n2 * 128 + r;
        gboff[i] = (size_t)ng * KP1 + k8 * 8;
        int nt = r >> 5;
        int colp = ((r & 31) + (jb << 2)) & 31;
        lo[i] = ((((jb << 2) + nt) << 1) + plane) * 512 + (colp + ((k8 & 1) << 5)) * 8;
    }

    const __bf16* Ah0 = hch + (size_t)(mt * 128 + s * 32 + l31) * KP1 + kbase + half8;
    const __bf16* Al0 = hcl + (size_t)(mt * 128 + s * 32 + l31) * KP1 + kbase + half8;

    bf16x8 rB[8];
    f32x16 acc[2];
#pragma unroll
    for (int nt = 0; nt < 2; ++nt)
#pragma unroll
        for (int r = 0; r < 16; ++r) acc[nt][r] = 0.0f;

#pragma unroll
    for (int i = 0; i < 8; ++i)
        rB[i] = *(const bf16x8*)(((i >= 4) ? w1l : w1h) + gboff[i] + kbase);
#pragma unroll
    for (int i = 0; i < 8; ++i) *(bf16x8*)(&Bb[0][lo[i]]) = rB[i];
    __syncthreads();

    for (int c = 0; c < 5; ++c) {
        int cur = c & 1;
        if (c < 4) {
            int k0 = kbase + (c + 1) * 128;
            bool tail = (c + 1 == 4);
#pragma unroll
            for (int i = 0; i < 8; ++i) {
                if (!tail || k8 < 2)
                    rB[i] = *(const bf16x8*)(((i >= 4) ? w1l : w1h) + gboff[i] + k0);
            }
        }
        int jmax = (c == 4) ? 1 : 8;
        for (int j = 0; j < jmax; ++j) {
            bf16x8 ah = *(const bf16x8*)(Ah0 + c * 128 + j * 16);
            bf16x8 al = *(const bf16x8*)(Al0 + c * 128 + j * 16);
            int cp = ((l31 + (j << 2)) & 31) + ((lane >> 5) << 5);
#pragma unroll
            for (int ntl = 0; ntl < 2; ++ntl) {
                int ntg = nh * 2 + ntl;
                const __bf16* bp = &Bb[cur][(((j << 2) + ntg) << 1) * 512 + cp * 8];
                bf16x8 bh = *(const bf16x8*)bp;
                bf16x8 bl = *(const bf16x8*)(bp + 512);
                acc[ntl] = __builtin_amdgcn_mfma_f32_32x32x16_bf16(ah, bh, acc[ntl], 0, 0, 0);
                acc[ntl] = __builtin_amdgcn_mfma_f32_32x32x16_bf16(ah, bl, acc[ntl], 0, 0, 0);
                acc[ntl] = __builtin_amdgcn_mfma_f32_32x32x16_bf16(al, bh, acc[ntl], 0, 0, 0);
            }
        }
        if (c < 4) {
#pragma unroll
            for (int i = 0; i < 8; ++i) *(bf16x8*)(&Bb[1 - cur][lo[i]]) = rB[i];
        }
        __syncthreads();
    }

#pragma unroll
    for (int ntl = 0; ntl < 2; ++ntl)
#pragma unroll
        for (int r = 0; r < 16; ++r) {
            int row = mt * 128 + s * 32 + (r & 3) + ((r >> 2) << 3) + ((lane >> 5) << 2);
            int col = n2 * 128 + nh * 64 + ntl * 32 + l31;
            part[((size_t)ks * 512 + row) * MDIM + col] = acc[ntl][r];
        }
}

// ---------------------------------------------------------------------------
// Head stage 3: e1 = relu(sum partials + b1); out = e1 @ W2 + b2
// ---------------------------------------------------------------------------
__global__ __launch_bounds__(256) void head3(const float* __restrict__ part,
                                             const float* __restrict__ b1,
                                             const float* __restrict__ W2,
                                             const float* __restrict__ b2,
                                             float* __restrict__ out) {
    int row = blockIdx.x;
    int tid = threadIdx.x;
    float sv = b1[tid];
#pragma unroll
    for (int ks = 0; ks < 4; ++ks)
        sv += part[((size_t)ks * 512 + row) * MDIM + tid];
    float e = fmaxf(sv, 0.0f);
    float p0 = e * W2[tid * 2 + 0];
    float p1 = e * W2[tid * 2 + 1];
#pragma unroll
    for (int off = 32; off > 0; off >>= 1) {
        p0 += __shfl_down(p0, off, 64);
        p1 += __shfl_down(p1, off, 64);
    }
    __shared__ float r0[4], r1[4];
    if ((tid & 63) == 0) { r0[tid >> 6] = p0; r1[tid >> 6] = p1; }
    __syncthreads();
    if (tid == 0) out[row * 2 + 0] = r0[0] + r0[1] + r0[2] + r0[3] + b2[0];
    if (tid == 1) out[row * 2 + 1] = r1[0] + r1[1] + r1[2] + r1[3] + b2[1];
}

// ---------------------------------------------------------------------------
extern "C" void kernel_launch(void* const* d_in, const int* in_sizes, int n_in,
                              void* d_out, int out_size, void* d_ws, size_t ws_size,
                              hipStream_t stream) {
    const int*   in1  = (const int*)d_in[0];
    const int*   in2  = (const int*)d_in[1];
    const int*   sl1  = (const int*)d_in[2];
    const int*   sl2  = (const int*)d_in[3];
    const float* emb  = (const float*)d_in[4];
    const float* kern = (const float*)d_in[5];
    const float* bias = (const float*)d_in[6];
    const float* W1   = (const float*)d_in[7];
    const float* b1   = (const float*)d_in[8];
    const float* W2   = (const float*)d_in[9];
    const float* b2   = (const float*)d_in[10];
    float* out = (float*)d_out;

    char* ws = (char*)d_ws;
    // ws layout (bytes):
    //   rowinfo i32[1024]         @ 0            (4096)
    //   step_done u32[16]         @ 4096
    //   h_state f32 [1024*512]    @ 2,097,152    (2,097,152)
    //   wf  bf16 frag             @ 6,291,456    (7,340,032)
    //   hch bf16 [512*2112]       @ 13,631,488   (2,162,688)
    //   hcl                       @ 15,794,176   (2,162,688)
    //   w1h bf16 [256*2112]       @ 17,956,864   (1,081,344)
    //   w1l                       @ 19,038,208   (1,081,344)
    //   part f32 [4*512*256]      @ 20,119,552   (2,097,152)
    //   embB bf16 [50000][768]    @ 23,068,672   (76,800,000)
    //   XfH bf16 61*[16][65536]   @ 100,663,296  (127,926,272) -> 228,589,568
    int*      rowinfo   = (int*)ws;
    unsigned* step_done = (unsigned*)(ws + 4096u);
    float*  h_state = (float*)(ws + 2097152u);
    __bf16* wf   = (__bf16*)(ws + 6291456u);
    __bf16* hch  = (__bf16*)(ws + 13631488u);
    __bf16* hcl  = (__bf16*)(ws + 15794176u);
    __bf16* w1h  = (__bf16*)(ws + 17956864u);
    __bf16* w1l  = (__bf16*)(ws + 19038208u);
    float*  part = (float*)(ws + 20119552u);
    __bf16* embB = (__bf16*)(ws + 23068672u);
    __bf16* XfH  = (__bf16*)(ws + 100663296u);

    // zero hch/hcl pad columns
    hipMemsetAsync(ws + 13631488u, 0, 4325376u, stream);
    // zero XfH region 0 (initial h = 0)
    hipMemsetAsync(ws + 100663296u, 0, 2097152u, stream);

    sort_rows<<<dim3(1), dim3(256), 0, stream>>>(sl1, sl2, rowinfo, step_done);
    prep_w<<<dim3(14 * 32), dim3(256), 0, stream>>>(kern, wf);
    prep_w1<<<dim3(33 * 4), dim3(256), 0, stream>>>(W1, w1h, w1l);
    prep_emb<<<dim3(9375), dim3(256), 0, stream>>>(emb, embB);

    lstm_all<<<dim3(512), dim3(256), 0, stream>>>(
        in1, in2, rowinfo, embB, bias, wf, XfH, step_done, h_state);

    head1<<<dim3(512), dim3(256), 0, stream>>>(h_state, sl1, sl2, hch, hcl);
    head2m<<<dim3(32), dim3(512), 0, stream>>>(hch, hcl, w1h, w1l, part);
    head3<<<dim3(512), dim3(256), 0, stream>>>(part, b1, W2, b2, out);
}